// Round 1
// 1271.784 us; speedup vs baseline: 1.0113x; 1.0113x over previous
//
#include <hip/hip_runtime.h>
#include <math.h>

#define B_ 64
#define N_ 512
#define P_ 512
#define E_ 128
#define F_ 512
#define L_ 6
#define SQRT_E_INV 0.08838834764831843f

typedef unsigned short u16;
typedef __attribute__((ext_vector_type(8))) short bf8;
typedef __attribute__((ext_vector_type(16))) float f16v;

__device__ inline u16 bf16r(float f) {
    unsigned u = __float_as_uint(f);
    u += 0x7fffu + ((u >> 16) & 1u);
    return (u16)(u >> 16);
}
__device__ inline float bf2f(u16 h) { return __uint_as_float((unsigned)h << 16); }

#define MFMA(a, b, c) __builtin_amdgcn_mfma_f32_32x32x16_bf16(a, b, c, 0, 0, 0)

// ===========================================================================
// qvk_k: fused q/v/k (QOFF=0) or decoder v/k (QOFF=1). Tile 64x128, K=128.
// A = x hi/lo split, B = weight hi/lo split (3 MFMA terms).
// Epilogue by blockIdx.y+QOFF: 0 = sigmoid->sq16[n][e], 1 = v->vt[b][e][n],
// 2 = exp->y2t[b][128+e][n].
// ===========================================================================
struct QP {
    const u16 *A0, *A1;
    const u16 *bh0, *bh1, *bh2, *bl0, *bl1, *bl2;
    u16 *sq16, *vt, *y2t;
};

template <int QOFF>
__launch_bounds__(256, 4) __global__ void qvk_k(QP p)
{
    const int tid = threadIdx.x;
    const int lane = tid & 63, wv = tid >> 6;
    const int wm = wv & 1, wn = wv >> 1;
    const int ln = lane & 31, hk = lane >> 5;
    const int row0 = blockIdx.x * 64;
    const int y = blockIdx.y;
    const u16* B0 = (y == 0) ? p.bh0 : (y == 1 ? p.bh1 : p.bh2);
    const u16* B1 = (y == 0) ? p.bl0 : (y == 1 ? p.bl1 : p.bl2);

    __shared__ __align__(16) u16 As[2][64][40];
    __shared__ __align__(16) u16 Bs[2][128][40];

    f16v acc[2];
#pragma unroll
    for (int nt = 0; nt < 2; ++nt)
#pragma unroll
        for (int q = 0; q < 16; ++q) acc[nt][q] = 0.f;

    const int r = tid >> 2, kq = tid & 3;
    for (int k0 = 0; k0 < 128; k0 += 32) {
        size_t ga = (size_t)(row0 + r) * 128 + k0 + kq * 8;
        *(uint4*)&As[0][r][kq * 8] = *(const uint4*)(p.A0 + ga);
        *(uint4*)&As[1][r][kq * 8] = *(const uint4*)(p.A1 + ga);
#pragma unroll
        for (int i = 0; i < 2; ++i) {
            int s = tid + i * 256;
            int rb = s >> 2, q = s & 3;
            size_t gb = (size_t)rb * 128 + k0 + q * 8;
            *(uint4*)&Bs[0][rb][q * 8] = *(const uint4*)(B0 + gb);
            *(uint4*)&Bs[1][rb][q * 8] = *(const uint4*)(B1 + gb);
        }
        __syncthreads();
#pragma unroll
        for (int s = 0; s < 2; ++s) {
            bf8 ah = *(const bf8*)&As[0][wm * 32 + ln][s * 16 + hk * 8];
            bf8 al = *(const bf8*)&As[1][wm * 32 + ln][s * 16 + hk * 8];
#pragma unroll
            for (int nt = 0; nt < 2; ++nt) {
                bf8 bh = *(const bf8*)&Bs[0][wn * 64 + nt * 32 + ln][s * 16 + hk * 8];
                bf8 bl = *(const bf8*)&Bs[1][wn * 64 + nt * 32 + ln][s * 16 + hk * 8];
                acc[nt] = MFMA(ah, bh, acc[nt]);
                acc[nt] = MFMA(ah, bl, acc[nt]);
                acc[nt] = MFMA(al, bh, acc[nt]);
            }
        }
        __syncthreads();
    }

    const int eid = y + QOFF;
#pragma unroll
    for (int nt = 0; nt < 2; ++nt) {
        int gn = wn * 64 + nt * 32 + ln;
#pragma unroll
        for (int g = 0; g < 4; ++g) {
            int rb = row0 + wm * 32 + g * 8 + hk * 4;
            if (eid == 0) {
#pragma unroll
                for (int rr = 0; rr < 4; ++rr) {
                    float v = acc[nt][g * 4 + rr];
                    v = 1.f / (1.f + __expf(-v));
                    p.sq16[(size_t)(rb + rr) * 128 + gn] = bf16r(v);
                }
            } else {
                int bb = rb >> 9, nb = rb & 511;
                u16 q4[4];
#pragma unroll
                for (int rr = 0; rr < 4; ++rr) {
                    float v = acc[nt][g * 4 + rr];
                    if (eid == 2) v = __expf(v);
                    q4[rr] = bf16r(v);
                }
                uint2 u;
                u.x = q4[0] | ((unsigned)q4[1] << 16);
                u.y = q4[2] | ((unsigned)q4[3] << 16);
                u16* dst = (eid == 1)
                    ? (p.vt + (size_t)bb * 65536 + (size_t)gn * 512 + nb)
                    : (p.y2t + (size_t)bb * 131072 + (size_t)(128 + gn) * 512 + nb);
                *(uint2*)dst = u;
            }
        }
    }
}

// ===========================================================================
// ffn_k: PH=1: ff1 = relu(h@W1+b1) -> bf16 [n][512]; PH=2: ff2 = ff1@W2+b2 -> f32
// ===========================================================================
struct FP {
    const u16 *A0, *A1;
    const u16 *B0, *B1;
    const float* bias;
    u16* o16; float* of;
};

template <int PH>
__launch_bounds__(256, 4) __global__ void ffn_k(FP p)
{
    constexpr int AS = (PH == 1) ? 2 : 1;
    constexpr int K = (PH == 1) ? 128 : 512;
    const int tid = threadIdx.x;
    const int lane = tid & 63, wv = tid >> 6;
    const int wm = wv & 1, wn = wv >> 1;
    const int ln = lane & 31, hk = lane >> 5;
    const int row0 = blockIdx.x * 64;
    const int colB0 = blockIdx.y * 128;

    __shared__ __align__(16) u16 As[AS][64][40];
    __shared__ __align__(16) u16 Bs[2][128][40];

    f16v acc[2];
#pragma unroll
    for (int nt = 0; nt < 2; ++nt)
#pragma unroll
        for (int q = 0; q < 16; ++q) acc[nt][q] = 0.f;

    const int r = tid >> 2, kq = tid & 3;
    for (int k0 = 0; k0 < K; k0 += 32) {
        size_t ga = (size_t)(row0 + r) * K + k0 + kq * 8;
        *(uint4*)&As[0][r][kq * 8] = *(const uint4*)(p.A0 + ga);
        if (AS == 2) *(uint4*)&As[1][r][kq * 8] = *(const uint4*)(p.A1 + ga);
#pragma unroll
        for (int i = 0; i < 2; ++i) {
            int s = tid + i * 256;
            int rb = s >> 2, q = s & 3;
            size_t gb = (size_t)(colB0 + rb) * K + k0 + q * 8;
            *(uint4*)&Bs[0][rb][q * 8] = *(const uint4*)(p.B0 + gb);
            *(uint4*)&Bs[1][rb][q * 8] = *(const uint4*)(p.B1 + gb);
        }
        __syncthreads();
#pragma unroll
        for (int s = 0; s < 2; ++s) {
            bf8 ah = *(const bf8*)&As[0][wm * 32 + ln][s * 16 + hk * 8];
            bf8 al;
            if (AS == 2) al = *(const bf8*)&As[1][wm * 32 + ln][s * 16 + hk * 8];
#pragma unroll
            for (int nt = 0; nt < 2; ++nt) {
                bf8 bh = *(const bf8*)&Bs[0][wn * 64 + nt * 32 + ln][s * 16 + hk * 8];
                bf8 bl = *(const bf8*)&Bs[1][wn * 64 + nt * 32 + ln][s * 16 + hk * 8];
                acc[nt] = MFMA(ah, bh, acc[nt]);
                acc[nt] = MFMA(ah, bl, acc[nt]);
                if (AS == 2) acc[nt] = MFMA(al, bh, acc[nt]);
            }
        }
        __syncthreads();
    }

#pragma unroll
    for (int nt = 0; nt < 2; ++nt) {
        int gcol = colB0 + wn * 64 + nt * 32 + ln;
        float bv = p.bias[gcol];
#pragma unroll
        for (int g = 0; g < 4; ++g) {
            int rb = row0 + wm * 32 + g * 8 + hk * 4;
#pragma unroll
            for (int rr = 0; rr < 4; ++rr) {
                float v = acc[nt][g * 4 + rr] + bv;
                if (PH == 1) {
                    v = fmaxf(v, 0.f);
                    p.o16[(size_t)(rb + rr) * 512 + gcol] = bf16r(v);
                } else {
                    p.of[(size_t)(rb + rr) * 128 + gcol] = v;
                }
            }
        }
    }
}

// ===========================================================================
// aft_k: pipelined AFT aggregation GEMM. C[bz] = exp(as*A (+mask)) @ B^T.
// Tile 64x128 (M x N), K=512, k-step 32, reg-staged LDS double-buffer:
// per step {issue global->reg loads; MFMA from buf[cur]; exp+ds_write
// buf[cur^1]; barrier}. The vmcnt wait lands inside the write phase, after
// the compute phase has covered most of the load latency.
// Grid 1024 = 4 blocks/CU (16 waves) vs old 512 = 2 blocks/CU.
// Block decomposition is XCD-clustered: the 8 row-blocks sharing one (y,bz)
// B half-tile get the same id%8 -> same XCD -> B panel is an L2 hit.
// ===========================================================================
struct AP {
    const float *A0, *A1;   // dist (fp32), mask (fp32, OPA==2 only)
    const u16* B0;          // y2t bf16 [bz][256][512]
    float* Cf;              // [bz][512][256] fp32
    const float *s1, *s2; int s2i;
};

template <int OPA>   // 1: exp(as*A), 2: exp(as*A + mask)
__launch_bounds__(256, 4) __global__ void aft_k(AP p)
{
    const int tid = threadIdx.x;
    const int lane = tid & 63, wv = tid >> 6;
    const int wm = wv & 1, wn = wv >> 1;
    const int ln = lane & 31, hk = lane >> 5;

    // id in [0,1024): xcd=id&7, slot=id>>3; x=slot&7 (row tile),
    // group g=(slot>>3)*8+xcd in [0,128); y=g&1 (col half), bz=g>>1 (batch).
    // All 8 x-blocks of a group share id%8 -> same XCD L2.
    const int id = blockIdx.x;
    const int xcd = id & 7, slot = id >> 3;
    const int x = slot & 7;
    const int grp = ((slot >> 3) << 3) | xcd;
    const int y = grp & 1;
    const int bz = grp >> 1;
    const int row0 = x * 64, colB0 = y * 128;

    __shared__ __align__(16) u16 As[2][64][40];
    __shared__ __align__(16) u16 Bs[2][128][40];

    f16v acc[2];
#pragma unroll
    for (int nt = 0; nt < 2; ++nt)
#pragma unroll
        for (int q = 0; q < 16; ++q) acc[nt][q] = 0.f;

    const float ascale = p.s1[0] * p.s2[p.s2i];
    const float* Af = p.A0 + (size_t)bz * 262144 + (size_t)row0 * 512;
    const float* Mf = (OPA == 2)
        ? (p.A1 + (size_t)bz * 262144 + (size_t)row0 * 512) : (const float*)0;
    const u16* Bb = p.B0 + (size_t)bz * 131072 + (size_t)colB0 * 512;

    const int r = tid >> 2, kq = tid & 3;    // A stage: 64 rows x 32 fp32
    const int rb = tid >> 1, hB = tid & 1;   // B stage: 128 rows x 32 bf16

    float fa[8], fm[8];
    uint4 vb0, vb1;

#define AFT_LOAD(K0)                                                          \
    {                                                                         \
        size_t ga = (size_t)r * 512 + (K0) + kq * 8;                          \
        *(float4*)&fa[0] = *(const float4*)(Af + ga);                         \
        *(float4*)&fa[4] = *(const float4*)(Af + ga + 4);                     \
        if (OPA == 2) {                                                       \
            *(float4*)&fm[0] = *(const float4*)(Mf + ga);                     \
            *(float4*)&fm[4] = *(const float4*)(Mf + ga + 4);                 \
        }                                                                     \
        size_t gb = (size_t)rb * 512 + (K0) + hB * 16;                        \
        vb0 = *(const uint4*)(Bb + gb);                                       \
        vb1 = *(const uint4*)(Bb + gb + 8);                                   \
    }

#define AFT_WRITE(BUF)                                                       \
    {                                                                         \
        float f[8];                                                           \
        _Pragma("unroll") for (int j = 0; j < 8; ++j) {                       \
            float t = (OPA == 2) ? fmaf(ascale, fa[j], fm[j]) : ascale * fa[j]; \
            f[j] = __expf(t);                                                 \
        }                                                                     \
        uint4 pk;                                                             \
        pk.x = bf16r(f[0]) | ((unsigned)bf16r(f[1]) << 16);                   \
        pk.y = bf16r(f[2]) | ((unsigned)bf16r(f[3]) << 16);                   \
        pk.z = bf16r(f[4]) | ((unsigned)bf16r(f[5]) << 16);                   \
        pk.w = bf16r(f[6]) | ((unsigned)bf16r(f[7]) << 16);                   \
        *(uint4*)&As[BUF][r][kq * 8] = pk;                                    \
        *(uint4*)&Bs[BUF][rb][hB * 16] = vb0;                                 \
        *(uint4*)&Bs[BUF][rb][hB * 16 + 8] = vb1;                             \
    }

#define AFT_COMPUTE(BUF)                                                     \
    {                                                                         \
        _Pragma("unroll") for (int s = 0; s < 2; ++s) {                       \
            bf8 ah = *(const bf8*)&As[BUF][wm * 32 + ln][s * 16 + hk * 8];    \
            _Pragma("unroll") for (int nt = 0; nt < 2; ++nt) {                \
                bf8 bh = *(const bf8*)&Bs[BUF][wn * 64 + nt * 32 + ln]        \
                                       [s * 16 + hk * 8];                     \
                acc[nt] = MFMA(ah, bh, acc[nt]);                              \
            }                                                                 \
        }                                                                     \
    }

    AFT_LOAD(0);
    AFT_WRITE(0);
    __syncthreads();

    int cur = 0;
    for (int k0 = 32; k0 < 512; k0 += 32) {
        AFT_LOAD(k0);
        AFT_COMPUTE(cur);
        AFT_WRITE(cur ^ 1);
        __syncthreads();
        cur ^= 1;
    }
    AFT_COMPUTE(cur);

#undef AFT_LOAD
#undef AFT_WRITE
#undef AFT_COMPUTE

    float* Cb = p.Cf + (size_t)bz * 131072;
#pragma unroll
    for (int nt = 0; nt < 2; ++nt) {
        int gn = colB0 + wn * 64 + nt * 32 + ln;
#pragma unroll
        for (int g4 = 0; g4 < 4; ++g4) {
            int rr0 = row0 + wm * 32 + g4 * 8 + hk * 4;
#pragma unroll
            for (int rr = 0; rr < 4; ++rr)
                Cb[(size_t)(rr0 + rr) * 256 + gn] = acc[nt][g4 * 4 + rr];
        }
    }
}

// ===========================================================================
// big_k: batched big-K GEMM, tile 64x256 (4 waves = 2x2, wave 32x128, nt=4).
// Only the score epilogue variant <0,1> is still used.
// ===========================================================================
struct GP {
    const void *A0, *A1;
    const u16 *B0, *B1;
    float* Cf;
    const float *cd, *cm;
    const float *s1, *s2; int s2i;
    int K, lda, ldb;
    long sA, sB;
};

template <int OPA, int OPC>
__launch_bounds__(256, OPC ? 3 : 4) __global__ void big_k(GP p)
{
    constexpr int AS = (OPA == 0) ? 2 : 1;
    constexpr int BS = (OPC == 1) ? 2 : 1;
    const int tid = threadIdx.x;
    const int lane = tid & 63, wv = tid >> 6;
    const int wm = wv & 1, wn = wv >> 1;
    const int ln = lane & 31, hk = lane >> 5;
    const int row0 = blockIdx.x * 64;
    const int colB0 = blockIdx.y * 256;
    const int bz = blockIdx.z;

    __shared__ __align__(16) u16 As[AS][64][40];
    __shared__ __align__(16) u16 Bs[BS][256][40];

    f16v acc[4];
#pragma unroll
    for (int nt = 0; nt < 4; ++nt)
#pragma unroll
        for (int q = 0; q < 16; ++q) acc[nt][q] = 0.f;

    float ascale = 0.f;
    if (OPA) ascale = p.s1[0] * p.s2[p.s2i];

    const int r = tid >> 2, kq = tid & 3;
    for (int k0 = 0; k0 < p.K; k0 += 32) {
        if (OPA == 0) {
            size_t ga = (size_t)bz * p.sA + (size_t)(row0 + r) * p.lda + k0 + kq * 8;
            *(uint4*)&As[0][r][kq * 8] = *(const uint4*)((const u16*)p.A0 + ga);
            *(uint4*)&As[AS - 1][r][kq * 8] = *(const uint4*)((const u16*)p.A1 + ga);
        } else {
            size_t ga = (size_t)bz * p.sA + (size_t)(row0 + r) * p.lda + k0 + kq * 8;
            const float* Af = (const float*)p.A0;
            float f[8];
            *(float4*)&f[0] = *(const float4*)(Af + ga);
            *(float4*)&f[4] = *(const float4*)(Af + ga + 4);
            if (OPA == 2) {
                const float* Mf = (const float*)p.A1;
                float m[8];
                *(float4*)&m[0] = *(const float4*)(Mf + ga);
                *(float4*)&m[4] = *(const float4*)(Mf + ga + 4);
#pragma unroll
                for (int j = 0; j < 8; ++j) f[j] = __expf(fmaf(ascale, f[j], m[j]));
            } else {
#pragma unroll
                for (int j = 0; j < 8; ++j) f[j] = __expf(ascale * f[j]);
            }
            uint4 pk;
            pk.x = bf16r(f[0]) | ((unsigned)bf16r(f[1]) << 16);
            pk.y = bf16r(f[2]) | ((unsigned)bf16r(f[3]) << 16);
            pk.z = bf16r(f[4]) | ((unsigned)bf16r(f[5]) << 16);
            pk.w = bf16r(f[6]) | ((unsigned)bf16r(f[7]) << 16);
            *(uint4*)&As[0][r][kq * 8] = pk;
        }
#pragma unroll
        for (int i = 0; i < 4; ++i) {
            size_t gb = (size_t)bz * p.sB + (size_t)(colB0 + tid) * p.ldb + k0 + i * 8;
            *(uint4*)&Bs[0][tid][i * 8] = *(const uint4*)(p.B0 + gb);
            if (BS == 2) *(uint4*)&Bs[1][tid][i * 8] = *(const uint4*)(p.B1 + gb);
        }
        __syncthreads();
#pragma unroll
        for (int s = 0; s < 2; ++s) {
            bf8 ah = *(const bf8*)&As[0][wm * 32 + ln][s * 16 + hk * 8];
            bf8 al;
            if (AS == 2) al = *(const bf8*)&As[1][wm * 32 + ln][s * 16 + hk * 8];
#pragma unroll
            for (int nt = 0; nt < 4; ++nt) {
                bf8 bh = *(const bf8*)&Bs[0][wn * 128 + nt * 32 + ln][s * 16 + hk * 8];
                acc[nt] = MFMA(ah, bh, acc[nt]);
                if (BS == 2) {
                    bf8 bl = *(const bf8*)&Bs[1][wn * 128 + nt * 32 + ln][s * 16 + hk * 8];
                    acc[nt] = MFMA(ah, bl, acc[nt]);
                    if (AS == 2) acc[nt] = MFMA(al, bh, acc[nt]);
                }
            }
        }
        __syncthreads();
    }

    float sp = (OPC == 1) ? p.s1[0] * p.s2[0] : 0.f;
#pragma unroll
    for (int nt = 0; nt < 4; ++nt) {
        int gn = (OPC == 1 ? colB0 : 0) + wn * 128 + nt * 32 + ln;
#pragma unroll
        for (int g = 0; g < 4; ++g) {
            int rb = row0 + wm * 32 + g * 8 + hk * 4;
#pragma unroll
            for (int rr = 0; rr < 4; ++rr) {
                float v = acc[nt][g * 4 + rr];
                if (OPC == 0) {
                    p.Cf[(size_t)bz * 131072 + (size_t)(rb + rr) * 256 + gn] = v;
                } else {
                    size_t ix = (size_t)bz * 262144 + (size_t)(rb + rr) * 512 + gn;
                    float sc = fmaf(v, SQRT_E_INV, sp * p.cd[ix]);
                    float e2 = __expf(2.f * sc);
                    float th = 1.f - 2.f / (e2 + 1.f);
                    p.Cf[ix] = 10.f * th + p.cm[ix];
                }
            }
        }
    }
}

// ===========================================================================
// ekv_k: y2t[b][e][n] = vt[b][e][n] * y2t[b][128+e][n]   (all bf16)
// ===========================================================================
__global__ void ekv_k(const u16* __restrict__ vt, u16* __restrict__ y2t)
{
    size_t t = (size_t)blockIdx.x * 256 + threadIdx.x;   // B*E*N/8 = 512K
    int b = (int)(t >> 13);
    int rem = (int)(t & 8191);
    int e = rem >> 6, n8 = rem & 63;
    const u16* pv = vt + (size_t)b * 65536 + (size_t)e * 512 + n8 * 8;
    const u16* pe = y2t + (size_t)b * 131072 + (size_t)(128 + e) * 512 + n8 * 8;
    u16* pd = y2t + (size_t)b * 131072 + (size_t)e * 512 + n8 * 8;
    uint4 v4 = *(const uint4*)pv;
    uint4 e4 = *(const uint4*)pe;
    const unsigned* vw = (const unsigned*)&v4;
    const unsigned* ew = (const unsigned*)&e4;
    uint4 o;
    unsigned* ow = (unsigned*)&o;
#pragma unroll
    for (int i = 0; i < 4; ++i) {
        float a0 = bf2f((u16)vw[i]) * bf2f((u16)ew[i]);
        float a1 = bf2f((u16)(vw[i] >> 16)) * bf2f((u16)(ew[i] >> 16));
        ow[i] = bf16r(a0) | ((unsigned)bf16r(a1) << 16);
    }
    *(uint4*)pd = o;
}

// ===========================================================================
// InstanceNorm over nodes, residual fused.
// MODE1: val = (ah+al) + sg16 * num/den ; MODE2: val = (ah+al) + ff2(f32)
// ===========================================================================
template <int MODE>
__launch_bounds__(256) __global__ void inorm_k(
    const u16* __restrict__ ah, const u16* __restrict__ al,
    const u16* __restrict__ sg16, const float* __restrict__ f1,
    const float* __restrict__ w2,
    const float* __restrict__ nw, const float* __restrict__ nbv,
    u16* __restrict__ oh, u16* __restrict__ ol)
{
    const int bb = blockIdx.x, e0 = blockIdx.y * 16;
    const int tid = threadIdx.x, el = tid & 3, no = tid >> 2;
    const size_t base = (size_t)bb * N_ * E_ + e0 + el * 4;

    float4 vals[8];
    float s1x = 0, s1y = 0, s1z = 0, s1w = 0;
    float s2x = 0, s2y = 0, s2z = 0, s2w = 0;
#pragma unroll
    for (int i = 0; i < 8; ++i) {
        int n = no * 8 + i;
        size_t ad = base + (size_t)n * E_;
        uint2 h2 = *(const uint2*)(ah + ad);
        uint2 l2 = *(const uint2*)(al + ad);
        float x0 = bf2f((u16)h2.x) + bf2f((u16)l2.x);
        float x1 = bf2f((u16)(h2.x >> 16)) + bf2f((u16)(l2.x >> 16));
        float x2 = bf2f((u16)h2.y) + bf2f((u16)l2.y);
        float x3 = bf2f((u16)(h2.y >> 16)) + bf2f((u16)(l2.y >> 16));
        float4 v;
        if (MODE == 1) {
            uint2 s2v = *(const uint2*)(sg16 + ad);
            float g0 = bf2f((u16)s2v.x), g1 = bf2f((u16)(s2v.x >> 16));
            float g2 = bf2f((u16)s2v.y), g3 = bf2f((u16)(s2v.y >> 16));
            size_t wb = ((size_t)bb * N_ + n) * 256 + e0 + el * 4;
            float4 nu = *(const float4*)(w2 + wb);
            float4 de = *(const float4*)(w2 + wb + 128);
            v.x = x0 + g0 * nu.x / de.x;
            v.y = x1 + g1 * nu.y / de.y;
            v.z = x2 + g2 * nu.z / de.z;
            v.w = x3 + g3 * nu.w / de.w;
        } else {
            float4 ff = *(const float4*)(f1 + ad);
            v.x = x0 + ff.x; v.y = x1 + ff.y; v.z = x2 + ff.z; v.w = x3 + ff.w;
        }
        vals[i] = v;
        s1x += v.x; s1y += v.y; s1z += v.z; s1w += v.w;
        s2x = fmaf(v.x, v.x, s2x); s2y = fmaf(v.y, v.y, s2y);
        s2z = fmaf(v.z, v.z, s2z); s2w = fmaf(v.w, v.w, s2w);
    }

    __shared__ float4 r1[256], r2[256];
    r1[tid] = make_float4(s1x, s1y, s1z, s1w);
    r2[tid] = make_float4(s2x, s2y, s2z, s2w);
    __syncthreads();
    for (int s = 128; s >= 4; s >>= 1) {
        if (tid < s) {
            float4 u = r1[tid], w = r1[tid + s];
            r1[tid] = make_float4(u.x + w.x, u.y + w.y, u.z + w.z, u.w + w.w);
            float4 pq = r2[tid], q = r2[tid + s];
            r2[tid] = make_float4(pq.x + q.x, pq.y + q.y, pq.z + q.z, pq.w + q.w);
        }
        __syncthreads();
    }
    __shared__ float4 mu_s[4], rs_s[4];
    if (tid < 4) {
        float4 m = r1[tid], q = r2[tid];
        m.x *= (1.f / N_); m.y *= (1.f / N_); m.z *= (1.f / N_); m.w *= (1.f / N_);
        q.x *= (1.f / N_); q.y *= (1.f / N_); q.z *= (1.f / N_); q.w *= (1.f / N_);
        float4 rs;
        rs.x = rsqrtf(q.x - m.x * m.x + 1e-5f);
        rs.y = rsqrtf(q.y - m.y * m.y + 1e-5f);
        rs.z = rsqrtf(q.z - m.z * m.z + 1e-5f);
        rs.w = rsqrtf(q.w - m.w * m.w + 1e-5f);
        mu_s[tid] = m; rs_s[tid] = rs;
    }
    __syncthreads();
    float4 mu = mu_s[el], rs = rs_s[el];
    float4 w4 = *(const float4*)(nw + e0 + el * 4);
    float4 b4 = *(const float4*)(nbv + e0 + el * 4);
#pragma unroll
    for (int i = 0; i < 8; ++i) {
        size_t ad = base + (size_t)(no * 8 + i) * E_;
        float4 v = vals[i];
        v.x = fmaf((v.x - mu.x) * rs.x, w4.x, b4.x);
        v.y = fmaf((v.y - mu.y) * rs.y, w4.y, b4.y);
        v.z = fmaf((v.z - mu.z) * rs.z, w4.z, b4.z);
        v.w = fmaf((v.w - mu.w) * rs.w, w4.w, b4.w);
        u16 h0 = bf16r(v.x), h1 = bf16r(v.y), h2v = bf16r(v.z), h3 = bf16r(v.w);
        u16 l0 = bf16r(v.x - bf2f(h0)), l1 = bf16r(v.y - bf2f(h1));
        u16 l2v = bf16r(v.z - bf2f(h2v)), l3 = bf16r(v.w - bf2f(h3));
        uint2 ph, pl;
        ph.x = h0 | ((unsigned)h1 << 16); ph.y = h2v | ((unsigned)h3 << 16);
        pl.x = l0 | ((unsigned)l1 << 16); pl.y = l2v | ((unsigned)l3 << 16);
        *(uint2*)(oh + ad) = ph;
        *(uint2*)(ol + ad) = pl;
    }
}

// ===========================================================================
__global__ void wprep_k(const float* __restrict__ W, u16* __restrict__ Th,
                        u16* __restrict__ Tl, int K, int N)
{
    const int z = blockIdx.z;
    const float* Wz = W + (size_t)z * K * N;
    u16* Hh = Th + (size_t)z * K * N;
    u16* Hl = Tl + (size_t)z * K * N;
    __shared__ float t[32][33];
    const int j = threadIdx.x & 31, i0 = threadIdx.x >> 5;
    const int k0 = blockIdx.x * 32, n0 = blockIdx.y * 32;
    for (int i = i0; i < 32; i += 8)
        t[i][j] = Wz[(size_t)(k0 + i) * N + n0 + j];
    __syncthreads();
    for (int i = i0; i < 32; i += 8) {
        float v = t[j][i];
        u16 h = bf16r(v);
        u16 l = bf16r(v - bf2f(h));
        size_t o = (size_t)(n0 + i) * K + k0 + j;
        Hh[o] = h; Hl[o] = l;
    }
}

__global__ void embed_k(const float* __restrict__ data, const float* __restrict__ W,
                        const float* __restrict__ bias,
                        u16* __restrict__ xh, u16* __restrict__ xl)
{
    size_t idx = (size_t)blockIdx.x * 256 + threadIdx.x;
    int e = idx & 127;
    size_t bn = idx >> 7;
    float v = fmaf(data[bn * 2], W[e], fmaf(data[bn * 2 + 1], W[128 + e], bias[e]));
    u16 h = bf16r(v);
    xh[idx] = h;
    xl[idx] = bf16r(v - bf2f(h));
}

__launch_bounds__(512) __global__
void gq_k(const u16* __restrict__ xh, const u16* __restrict__ xl,
          const float* __restrict__ dWq, float* __restrict__ gq)
{
    int b = blockIdx.x;
    int tid = threadIdx.x;
    int e = tid & 127, qd = tid >> 7;
    float s = 0.f;
    for (int n = qd; n < N_; n += 4) {
        size_t ix = ((size_t)b * N_ + n) * E_ + e;
        s += bf2f(xh[ix]) + bf2f(xl[ix]);
    }
    __shared__ float part[512];
    __shared__ float gm[128];
    part[tid] = s;
    __syncthreads();
    if (tid < 128)
        gm[tid] = (part[tid] + part[tid + 128] + part[tid + 256] + part[tid + 384]) *
                  (1.f / N_);
    __syncthreads();
    if (tid < 128) {
        float acc = 0.f;
        for (int kk = 0; kk < 128; ++kk) acc = fmaf(gm[kk], dWq[kk * 128 + tid], acc);
        gq[b * 128 + tid] = acc;
    }
}

__global__ void dec_aft_k(const float* __restrict__ gq, const float* __restrict__ cap,
                          const float* __restrict__ dWq, const float* __restrict__ w2,
                          u16* __restrict__ oh, u16* __restrict__ ol)
{
    size_t idx = (size_t)blockIdx.x * 256 + threadIdx.x;
    int e = idx & 127;
    size_t bp = idx >> 7;
    int b = (int)(bp >> 9);
    float q = fmaf(cap[bp], dWq[128 * 128 + e], gq[b * 128 + e]);
    float sg = 1.f / (1.f + __expf(-q));
    float v = sg * w2[bp * 256 + e] / w2[bp * 256 + 128 + e];
    u16 h = bf16r(v);
    oh[idx] = h;
    ol[idx] = bf16r(v - bf2f(h));
}

__launch_bounds__(256) __global__ void softmax_k(float* __restrict__ out)
{
    int row = blockIdx.x * 4 + (threadIdx.x >> 6);
    int lane = threadIdx.x & 63;
    float* p = out + (size_t)row * 512 + lane * 8;
    float4 v0 = *(float4*)p;
    float4 v1 = *(float4*)(p + 4);
    float m = fmaxf(fmaxf(fmaxf(v0.x, v0.y), fmaxf(v0.z, v0.w)),
                    fmaxf(fmaxf(v1.x, v1.y), fmaxf(v1.z, v1.w)));
#pragma unroll
    for (int o = 32; o; o >>= 1) m = fmaxf(m, __shfl_xor(m, o));
    v0.x = __expf(v0.x - m); v0.y = __expf(v0.y - m);
    v0.z = __expf(v0.z - m); v0.w = __expf(v0.w - m);
    v1.x = __expf(v1.x - m); v1.y = __expf(v1.y - m);
    v1.z = __expf(v1.z - m); v1.w = __expf(v1.w - m);
    float s = v0.x + v0.y + v0.z + v0.w + v1.x + v1.y + v1.z + v1.w;
#pragma unroll
    for (int o = 32; o; o >>= 1) s += __shfl_xor(s, o);
    float inv = 1.f / s;
    v0.x *= inv; v0.y *= inv; v0.z *= inv; v0.w *= inv;
    v1.x *= inv; v1.y *= inv; v1.z *= inv; v1.w *= inv;
    *(float4*)p = v0;
    *(float4*)(p + 4) = v1;
}

// ===========================================================================
extern "C" void kernel_launch(void* const* d_in, const int* in_sizes, int n_in,
                              void* d_out, int out_size, void* d_ws, size_t ws_size,
                              hipStream_t stream)
{
    const float* data      = (const float*)d_in[0];
    const float* dist      = (const float*)d_in[1];
    const float* cur_dist  = (const float*)d_in[2];
    const float* capacity  = (const float*)d_in[3];
    const float* ninf      = (const float*)d_in[4];
    const float* log_scale = (const float*)d_in[5];
    const float* emb_W     = (const float*)d_in[6];
    const float* emb_b     = (const float*)d_in[7];
    const float* Wq        = (const float*)d_in[8];
    const float* Wk        = (const float*)d_in[9];
    const float* Wv        = (const float*)d_in[10];
    const float* aft_alpha = (const float*)d_in[11];
    const float* n1_w      = (const float*)d_in[12];
    const float* n1_b      = (const float*)d_in[13];
    const float* ffW1      = (const float*)d_in[14];
    const float* ffb1      = (const float*)d_in[15];
    const float* ffW2      = (const float*)d_in[16];
    const float* ffb2      = (const float*)d_in[17];
    const float* n2_w      = (const float*)d_in[18];
    const float* n2_b      = (const float*)d_in[19];
    const float* dWq       = (const float*)d_in[20];
    const float* dWk       = (const float*)d_in[21];
    const float* dWv       = (const float*)d_in[22];
    const float* dec_alpha = (const float*)d_in[23];
    const float* p_alpha   = (const float*)d_in[24];
    float* out = (float*)d_out;

    char* W = (char*)d_ws;
    size_t off = 0;
    auto take = [&](size_t n) { void* pp = W + off; off += (n + 255) & ~(size_t)255; return pp; };
    const size_t SZP = (size_t)B_ * N_ * E_ * 2;   // 8 MB bf16 plane

    u16* xh   = (u16*)take(SZP);
    u16* xl   = (u16*)take(SZP);
    u16* hh   = (u16*)take(SZP);     // decoder: aft hi
    u16* hl   = (u16*)take(SZP);     // decoder: aft lo
    u16* sq16 = (u16*)take(SZP);     // + y2t + pad = 32MB region for ff1
    u16* y2t  = (u16*)take(2 * SZP); // [B][256][512] bf16 = 16 MB
    (void)take(SZP);                 // pad so ff1 (32MB) fits from sq16 base
    float* w2 = (float*)take((size_t)B_ * N_ * 256 * 4);  // 32 MB fp32 (vt/ff2 alias)
    u16* wqt_h = (u16*)take(196608); u16* wqt_l = (u16*)take(196608);
    u16* wkt_h = (u16*)take(196608); u16* wkt_l = (u16*)take(196608);
    u16* wvt_h = (u16*)take(196608); u16* wvt_l = (u16*)take(196608);
    u16* w1t_h = (u16*)take(786432); u16* w1t_l = (u16*)take(786432);
    u16* w2t_h = (u16*)take(786432); u16* w2t_l = (u16*)take(786432);
    u16* dkt_h = (u16*)take(32768);  u16* dkt_l = (u16*)take(32768);
    u16* dvt_h = (u16*)take(32768);  u16* dvt_l = (u16*)take(32768);
    float* gq = (float*)take(32768);
    if (ws_size < off) return;

    u16* vt = (u16*)w2;          // 8MB, dead before w2 written
    u16* ff1 = sq16;             // 32MB spanning sq16+y2t+pad (all dead at FF1 time)
    float* ff2 = w2;             // 16MB, w2 dead after inorm1

    // ---- weight prep ----
    wprep_k<<<dim3(4, 4, 6), 256, 0, stream>>>(Wq, wqt_h, wqt_l, 128, 128);
    wprep_k<<<dim3(4, 4, 6), 256, 0, stream>>>(Wk, wkt_h, wkt_l, 128, 128);
    wprep_k<<<dim3(4, 4, 6), 256, 0, stream>>>(Wv, wvt_h, wvt_l, 128, 128);
    wprep_k<<<dim3(4, 16, 6), 256, 0, stream>>>(ffW1, w1t_h, w1t_l, 128, 512);
    wprep_k<<<dim3(16, 4, 6), 256, 0, stream>>>(ffW2, w2t_h, w2t_l, 512, 128);
    wprep_k<<<dim3(4, 4, 1), 256, 0, stream>>>(dWk, dkt_h, dkt_l, 128, 128);
    wprep_k<<<dim3(4, 4, 1), 256, 0, stream>>>(dWv, dvt_h, dvt_l, 128, 128);

    embed_k<<<16384, 256, 0, stream>>>(data, emb_W, emb_b, xh, xl);

    for (int l = 0; l < L_; ++l) {
        QP qp{};
        qp.A0 = xh; qp.A1 = xl;
        qp.bh0 = wqt_h + l * 16384; qp.bl0 = wqt_l + l * 16384;
        qp.bh1 = wvt_h + l * 16384; qp.bl1 = wvt_l + l * 16384;
        qp.bh2 = wkt_h + l * 16384; qp.bl2 = wkt_l + l * 16384;
        qp.sq16 = sq16; qp.vt = vt; qp.y2t = y2t;
        qvk_k<0><<<dim3(512, 3), 256, 0, stream>>>(qp);
        ekv_k<<<2048, 256, 0, stream>>>(vt, y2t);

        AP ap{};
        ap.A0 = dist; ap.B0 = y2t; ap.Cf = w2;
        ap.s1 = log_scale; ap.s2 = aft_alpha; ap.s2i = l;
        aft_k<1><<<1024, 256, 0, stream>>>(ap);

        inorm_k<1><<<dim3(B_, 8), 256, 0, stream>>>(
            xh, xl, sq16, nullptr, w2, n1_w + l * 128, n1_b + l * 128, hh, hl);

        FP fp{};
        fp.A0 = hh; fp.A1 = hl;
        fp.B0 = w1t_h + l * 65536; fp.B1 = w1t_l + l * 65536;
        fp.bias = ffb1 + l * 512; fp.o16 = ff1;
        ffn_k<1><<<dim3(512, 4), 256, 0, stream>>>(fp);

        fp = FP{};
        fp.A0 = ff1;
        fp.B0 = w2t_h + l * 65536; fp.B1 = w2t_l + l * 65536;
        fp.bias = ffb2 + l * 128; fp.of = ff2;
        ffn_k<2><<<dim3(512, 1), 256, 0, stream>>>(fp);

        inorm_k<2><<<dim3(B_, 8), 256, 0, stream>>>(
            hh, hl, nullptr, ff2, nullptr, n2_w + l * 128, n2_b + l * 128, xh, xl);
    }

    // ---- decoder ---- (enc = xh/xl)
    {
        QP qp{};
        qp.A0 = xh; qp.A1 = xl;
        qp.bh0 = dvt_h; qp.bl0 = dvt_l;   // y=0 -> eid1 (vt)
        qp.bh1 = dkt_h; qp.bl1 = dkt_l;   // y=1 -> eid2 (ek)
        qp.vt = vt; qp.y2t = y2t;
        qvk_k<1><<<dim3(512, 2), 256, 0, stream>>>(qp);
        ekv_k<<<2048, 256, 0, stream>>>(vt, y2t);
        gq_k<<<B_, 512, 0, stream>>>(xh, xl, dWq, gq);

        AP ap{};
        ap.A0 = cur_dist; ap.A1 = ninf; ap.B0 = y2t; ap.Cf = w2;
        ap.s1 = log_scale; ap.s2 = dec_alpha; ap.s2i = 0;
        aft_k<2><<<1024, 256, 0, stream>>>(ap);

        dec_aft_k<<<16384, 256, 0, stream>>>(gq, capacity, dWq, w2, hh, hl);

        GP gp{};
        gp.A0 = hh; gp.A1 = hl; gp.B0 = xh; gp.B1 = xl;
        gp.Cf = out; gp.cd = cur_dist; gp.cm = ninf;
        gp.s1 = log_scale; gp.s2 = p_alpha; gp.s2i = 0;
        gp.K = 128; gp.lda = 128; gp.ldb = 128;
        gp.sA = 65536; gp.sB = 65536;
        big_k<0, 1><<<dim3(8, 2, 64), 256, 0, stream>>>(gp);

        softmax_k<<<8192, 256, 0, stream>>>(out);
    }
}

// Round 2
// 1169.585 us; speedup vs baseline: 1.0996x; 1.0874x over previous
//
#include <hip/hip_runtime.h>
#include <math.h>

#define B_ 64
#define N_ 512
#define P_ 512
#define E_ 128
#define F_ 512
#define L_ 6
#define SQRT_E_INV 0.08838834764831843f

typedef unsigned short u16;
typedef __attribute__((ext_vector_type(8))) short bf8;
typedef __attribute__((ext_vector_type(16))) float f16v;

__device__ inline u16 bf16r(float f) {
    unsigned u = __float_as_uint(f);
    u += 0x7fffu + ((u >> 16) & 1u);
    return (u16)(u >> 16);
}
__device__ inline float bf2f(u16 h) { return __uint_as_float((unsigned)h << 16); }

#define MFMA(a, b, c) __builtin_amdgcn_mfma_f32_32x32x16_bf16(a, b, c, 0, 0, 0)

// ===========================================================================
// qvk_q_k: q = x @ Wq, epilogue sigmoid -> sq16[b][n][e] (bf16).
// Tile 64x128, K=128, A/B hi-lo split (3 MFMA terms).
// ===========================================================================
struct QQ {
    const u16 *A0, *A1, *B0, *B1;
    u16* sq16;
};

__launch_bounds__(256, 4) __global__ void qvk_q_k(QQ p)
{
    const int tid = threadIdx.x;
    const int lane = tid & 63, wv = tid >> 6;
    const int wm = wv & 1, wn = wv >> 1;
    const int ln = lane & 31, hk = lane >> 5;
    const int row0 = blockIdx.x * 64;

    __shared__ __align__(16) u16 As[2][64][40];
    __shared__ __align__(16) u16 Bs[2][128][40];

    f16v acc[2];
#pragma unroll
    for (int nt = 0; nt < 2; ++nt)
#pragma unroll
        for (int q = 0; q < 16; ++q) acc[nt][q] = 0.f;

    const int r = tid >> 2, kq = tid & 3;
    for (int k0 = 0; k0 < 128; k0 += 32) {
        size_t ga = (size_t)(row0 + r) * 128 + k0 + kq * 8;
        *(uint4*)&As[0][r][kq * 8] = *(const uint4*)(p.A0 + ga);
        *(uint4*)&As[1][r][kq * 8] = *(const uint4*)(p.A1 + ga);
#pragma unroll
        for (int i = 0; i < 2; ++i) {
            int s = tid + i * 256;
            int rb = s >> 2, q = s & 3;
            size_t gb = (size_t)rb * 128 + k0 + q * 8;
            *(uint4*)&Bs[0][rb][q * 8] = *(const uint4*)(p.B0 + gb);
            *(uint4*)&Bs[1][rb][q * 8] = *(const uint4*)(p.B1 + gb);
        }
        __syncthreads();
#pragma unroll
        for (int s = 0; s < 2; ++s) {
            bf8 ah = *(const bf8*)&As[0][wm * 32 + ln][s * 16 + hk * 8];
            bf8 al = *(const bf8*)&As[1][wm * 32 + ln][s * 16 + hk * 8];
#pragma unroll
            for (int nt = 0; nt < 2; ++nt) {
                bf8 bh = *(const bf8*)&Bs[0][wn * 64 + nt * 32 + ln][s * 16 + hk * 8];
                bf8 bl = *(const bf8*)&Bs[1][wn * 64 + nt * 32 + ln][s * 16 + hk * 8];
                acc[nt] = MFMA(ah, bh, acc[nt]);
                acc[nt] = MFMA(ah, bl, acc[nt]);
                acc[nt] = MFMA(al, bh, acc[nt]);
            }
        }
        __syncthreads();
    }

#pragma unroll
    for (int nt = 0; nt < 2; ++nt) {
        int gn = wn * 64 + nt * 32 + ln;
#pragma unroll
        for (int g = 0; g < 4; ++g) {
            int rb = row0 + wm * 32 + g * 8 + hk * 4;
#pragma unroll
            for (int rr = 0; rr < 4; ++rr) {
                float v = acc[nt][g * 4 + rr];
                v = 1.f / (1.f + __expf(-v));
                p.sq16[(size_t)(rb + rr) * 128 + gn] = bf16r(v);
            }
        }
    }
}

// ===========================================================================
// qvk_vk_k: fused v = x@Wv and k = x@Wk in one block; epilogue writes
// ek = bf16(exp(k)) -> y2t[b][128+e][n] and ekv = bf16(bf16(v)*ek)
// -> y2t[b][e][n]. Replaces separate v-block, k-block and ekv_k.
// ===========================================================================
struct QV {
    const u16 *A0, *A1;
    const u16 *vh, *vl, *kh, *kl;
    u16* y2t;
};

__launch_bounds__(256, 3) __global__ void qvk_vk_k(QV p)
{
    const int tid = threadIdx.x;
    const int lane = tid & 63, wv = tid >> 6;
    const int wm = wv & 1, wn = wv >> 1;
    const int ln = lane & 31, hk = lane >> 5;
    const int row0 = blockIdx.x * 64;

    __shared__ __align__(16) u16 As[2][64][40];
    __shared__ __align__(16) u16 Bs[4][128][40];   // vh, vl, kh, kl

    f16v av[2], ak[2];
#pragma unroll
    for (int nt = 0; nt < 2; ++nt)
#pragma unroll
        for (int q = 0; q < 16; ++q) { av[nt][q] = 0.f; ak[nt][q] = 0.f; }

    const int r = tid >> 2, kq = tid & 3;
    for (int k0 = 0; k0 < 128; k0 += 32) {
        size_t ga = (size_t)(row0 + r) * 128 + k0 + kq * 8;
        *(uint4*)&As[0][r][kq * 8] = *(const uint4*)(p.A0 + ga);
        *(uint4*)&As[1][r][kq * 8] = *(const uint4*)(p.A1 + ga);
#pragma unroll
        for (int pl = 0; pl < 4; ++pl) {
            const u16* src = (pl == 0) ? p.vh : (pl == 1) ? p.vl
                             : (pl == 2) ? p.kh : p.kl;
#pragma unroll
            for (int i = 0; i < 2; ++i) {
                int s = tid + i * 256;           // [0,512): 128 rows x 4 quads
                int rb = s >> 2, q = s & 3;
                *(uint4*)&Bs[pl][rb][q * 8] =
                    *(const uint4*)(src + (size_t)rb * 128 + k0 + q * 8);
            }
        }
        __syncthreads();
#pragma unroll
        for (int s = 0; s < 2; ++s) {
            bf8 ah = *(const bf8*)&As[0][wm * 32 + ln][s * 16 + hk * 8];
            bf8 al = *(const bf8*)&As[1][wm * 32 + ln][s * 16 + hk * 8];
#pragma unroll
            for (int nt = 0; nt < 2; ++nt) {
                const int br = wn * 64 + nt * 32 + ln, sc = s * 16 + hk * 8;
                bf8 bvh = *(const bf8*)&Bs[0][br][sc];
                bf8 bvl = *(const bf8*)&Bs[1][br][sc];
                bf8 bkh = *(const bf8*)&Bs[2][br][sc];
                bf8 bkl = *(const bf8*)&Bs[3][br][sc];
                av[nt] = MFMA(ah, bvh, av[nt]);
                av[nt] = MFMA(ah, bvl, av[nt]);
                av[nt] = MFMA(al, bvh, av[nt]);
                ak[nt] = MFMA(ah, bkh, ak[nt]);
                ak[nt] = MFMA(ah, bkl, ak[nt]);
                ak[nt] = MFMA(al, bkh, ak[nt]);
            }
        }
        __syncthreads();
    }

#pragma unroll
    for (int nt = 0; nt < 2; ++nt) {
        int gn = wn * 64 + nt * 32 + ln;
#pragma unroll
        for (int g = 0; g < 4; ++g) {
            int rb = row0 + wm * 32 + g * 8 + hk * 4;
            int bb = rb >> 9, nb = rb & 511;
            u16 pe[4], pv[4];
#pragma unroll
            for (int rr = 0; rr < 4; ++rr) {
                u16 hv = bf16r(av[nt][g * 4 + rr]);
                u16 he = bf16r(__expf(ak[nt][g * 4 + rr]));
                pe[rr] = he;
                pv[rr] = bf16r(bf2f(hv) * bf2f(he));
            }
            uint2 ue, uv;
            ue.x = pe[0] | ((unsigned)pe[1] << 16);
            ue.y = pe[2] | ((unsigned)pe[3] << 16);
            uv.x = pv[0] | ((unsigned)pv[1] << 16);
            uv.y = pv[2] | ((unsigned)pv[3] << 16);
            *(uint2*)(p.y2t + (size_t)bb * 131072 + (size_t)gn * 512 + nb) = uv;
            *(uint2*)(p.y2t + (size_t)bb * 131072 + (size_t)(128 + gn) * 512 + nb) = ue;
        }
    }
}

// ===========================================================================
// aft2_k: AFT aggregation with num AND den in one block.
// C_num = exp(as*A(+M)) @ ekv^T, C_den = same @ ek^T; out = [sg*]num/den
// written as bf16 hi/lo planes [b][n][e]. Tile 64 rows x 128 e (num+den =
// 256 B-rows), K=512 step 32, reg-staged LDS double buffer.
// Grid 512, XCD-grouped: all 8 row-blocks of a bz on one XCD (B L2-shared).
// ===========================================================================
struct AP2 {
    const float *A0, *A1;    // dist / cur_dist, mask (OPA==2)
    const u16 *B0, *sq;      // y2t, sigmoid plane (SG==1)
    u16 *gh, *gl;
    const float *s1, *s2; int s2i;
};

template <int OPA, int SG>   // OPA1: exp(as*A); OPA2: exp(as*A + M)
__launch_bounds__(256, 2) __global__ void aft2_k(AP2 p)
{
    const int tid = threadIdx.x;
    const int lane = tid & 63, wv = tid >> 6;
    const int wm = wv & 1, wn = wv >> 1;
    const int ln = lane & 31, hk = lane >> 5;

    const int id = blockIdx.x;
    const int xcd = id & 7, slot = id >> 3;
    const int bz = xcd * 8 + (slot >> 3);
    const int row0 = (slot & 7) * 64;

    __shared__ __align__(16) u16 As[2][64][40];
    __shared__ __align__(16) u16 Bs[2][256][40];

    f16v acc[4];
#pragma unroll
    for (int j = 0; j < 4; ++j)
#pragma unroll
        for (int q = 0; q < 16; ++q) acc[j][q] = 0.f;

    const float ascale = p.s1[0] * p.s2[p.s2i];
    const float* Af = p.A0 + (size_t)bz * 262144 + (size_t)row0 * 512;
    const float* Mf = (OPA == 2)
        ? (p.A1 + (size_t)bz * 262144 + (size_t)row0 * 512) : (const float*)0;
    const u16* Bb = p.B0 + (size_t)bz * 131072;

    const int r = tid >> 2, kq = tid & 3;    // A: 64 rows x 32 fp32
    float fa[8], fm[8];
    uint4 vb[4];

#define AFT_LOAD(K0)                                                          \
    {                                                                         \
        size_t ga = (size_t)r * 512 + (K0) + kq * 8;                          \
        *(float4*)&fa[0] = *(const float4*)(Af + ga);                         \
        *(float4*)&fa[4] = *(const float4*)(Af + ga + 4);                     \
        if (OPA == 2) {                                                       \
            *(float4*)&fm[0] = *(const float4*)(Mf + ga);                     \
            *(float4*)&fm[4] = *(const float4*)(Mf + ga + 4);                 \
        }                                                                     \
        size_t gb = (size_t)tid * 512 + (K0);                                 \
        _Pragma("unroll") for (int q = 0; q < 4; ++q)                         \
            vb[q] = *(const uint4*)(Bb + gb + q * 8);                         \
    }

#define AFT_WRITE(BUF)                                                        \
    {                                                                         \
        float f[8];                                                           \
        _Pragma("unroll") for (int j = 0; j < 8; ++j) {                       \
            float t = (OPA == 2) ? fmaf(ascale, fa[j], fm[j]) : ascale * fa[j]; \
            f[j] = __expf(t);                                                 \
        }                                                                     \
        uint4 pk;                                                             \
        pk.x = bf16r(f[0]) | ((unsigned)bf16r(f[1]) << 16);                   \
        pk.y = bf16r(f[2]) | ((unsigned)bf16r(f[3]) << 16);                   \
        pk.z = bf16r(f[4]) | ((unsigned)bf16r(f[5]) << 16);                   \
        pk.w = bf16r(f[6]) | ((unsigned)bf16r(f[7]) << 16);                   \
        *(uint4*)&As[BUF][r][kq * 8] = pk;                                    \
        _Pragma("unroll") for (int q = 0; q < 4; ++q)                         \
            *(uint4*)&Bs[BUF][tid][q * 8] = vb[q];                            \
    }

#define AFT_COMPUTE(BUF)                                                      \
    {                                                                         \
        _Pragma("unroll") for (int s = 0; s < 2; ++s) {                       \
            bf8 ah = *(const bf8*)&As[BUF][wm * 32 + ln][s * 16 + hk * 8];    \
            _Pragma("unroll") for (int j = 0; j < 4; ++j) {                   \
                int br = ((j >> 1) << 7) + wn * 64 + ((j & 1) << 5) + ln;     \
                bf8 bh = *(const bf8*)&Bs[BUF][br][s * 16 + hk * 8];          \
                acc[j] = MFMA(ah, bh, acc[j]);                                \
            }                                                                 \
        }                                                                     \
    }

    AFT_LOAD(0);
    AFT_WRITE(0);
    __syncthreads();

    int cur = 0;
    for (int k0 = 32; k0 < 512; k0 += 32) {
        AFT_LOAD(k0);
        AFT_COMPUTE(cur);
        AFT_WRITE(cur ^ 1);
        __syncthreads();
        cur ^= 1;
    }
    AFT_COMPUTE(cur);

#undef AFT_LOAD
#undef AFT_WRITE
#undef AFT_COMPUTE

    const u16* sqb = SG ? (p.sq + (size_t)bz * 65536) : (const u16*)0;
    u16* ghb = p.gh + (size_t)bz * 65536;
    u16* glb = p.gl + (size_t)bz * 65536;
#pragma unroll
    for (int j = 0; j < 2; ++j) {
        int e = wn * 64 + j * 32 + ln;
#pragma unroll
        for (int g = 0; g < 4; ++g) {
#pragma unroll
            for (int rr = 0; rr < 4; ++rr) {
                int row = row0 + wm * 32 + g * 8 + hk * 4 + rr;
                float num = acc[j][g * 4 + rr];
                float den = acc[j + 2][g * 4 + rr];
                float pv = num / den;
                if (SG) pv *= bf2f(sqb[(size_t)row * 128 + e]);
                u16 hi = bf16r(pv);
                ghb[(size_t)row * 128 + e] = hi;
                glb[(size_t)row * 128 + e] = bf16r(pv - bf2f(hi));
            }
        }
    }
}

// ===========================================================================
// ffn_k: PH=1: ff1 = relu(h@W1+b1) -> bf16 [n][512] (1-D XCD-grouped grid);
// PH=2: ff2 = ff1@W2+b2 -> f32
// ===========================================================================
struct FP {
    const u16 *A0, *A1;
    const u16 *B0, *B1;
    const float* bias;
    u16* o16; float* of;
};

template <int PH>
__launch_bounds__(256, 4) __global__ void ffn_k(FP p)
{
    constexpr int AS = (PH == 1) ? 2 : 1;
    constexpr int K = (PH == 1) ? 128 : 512;
    const int tid = threadIdx.x;
    const int lane = tid & 63, wv = tid >> 6;
    const int wm = wv & 1, wn = wv >> 1;
    const int ln = lane & 31, hk = lane >> 5;
    int row0, colB0;
    if (PH == 1) {
        // 2048 blocks; 4 col-blocks sharing an A tile land on the same XCD.
        const int id = blockIdx.x;
        const int w = (id & 7) * 256 + (id >> 3);
        colB0 = (w & 3) * 128;
        row0 = (w >> 2) * 64;
    } else {
        row0 = blockIdx.x * 64;
        colB0 = 0;
    }

    __shared__ __align__(16) u16 As[AS][64][40];
    __shared__ __align__(16) u16 Bs[2][128][40];

    f16v acc[2];
#pragma unroll
    for (int nt = 0; nt < 2; ++nt)
#pragma unroll
        for (int q = 0; q < 16; ++q) acc[nt][q] = 0.f;

    const int r = tid >> 2, kq = tid & 3;
    for (int k0 = 0; k0 < K; k0 += 32) {
        size_t ga = (size_t)(row0 + r) * K + k0 + kq * 8;
        *(uint4*)&As[0][r][kq * 8] = *(const uint4*)(p.A0 + ga);
        if (AS == 2) *(uint4*)&As[1][r][kq * 8] = *(const uint4*)(p.A1 + ga);
#pragma unroll
        for (int i = 0; i < 2; ++i) {
            int s = tid + i * 256;
            int rb = s >> 2, q = s & 3;
            size_t gb = (size_t)(colB0 + rb) * K + k0 + q * 8;
            *(uint4*)&Bs[0][rb][q * 8] = *(const uint4*)(p.B0 + gb);
            *(uint4*)&Bs[1][rb][q * 8] = *(const uint4*)(p.B1 + gb);
        }
        __syncthreads();
#pragma unroll
        for (int s = 0; s < 2; ++s) {
            bf8 ah = *(const bf8*)&As[0][wm * 32 + ln][s * 16 + hk * 8];
            bf8 al;
            if (AS == 2) al = *(const bf8*)&As[1][wm * 32 + ln][s * 16 + hk * 8];
#pragma unroll
            for (int nt = 0; nt < 2; ++nt) {
                bf8 bh = *(const bf8*)&Bs[0][wn * 64 + nt * 32 + ln][s * 16 + hk * 8];
                bf8 bl = *(const bf8*)&Bs[1][wn * 64 + nt * 32 + ln][s * 16 + hk * 8];
                acc[nt] = MFMA(ah, bh, acc[nt]);
                acc[nt] = MFMA(ah, bl, acc[nt]);
                if (AS == 2) acc[nt] = MFMA(al, bh, acc[nt]);
            }
        }
        __syncthreads();
    }

#pragma unroll
    for (int nt = 0; nt < 2; ++nt) {
        int gcol = colB0 + wn * 64 + nt * 32 + ln;
        float bv = p.bias[gcol];
#pragma unroll
        for (int g = 0; g < 4; ++g) {
            int rb = row0 + wm * 32 + g * 8 + hk * 4;
#pragma unroll
            for (int rr = 0; rr < 4; ++rr) {
                float v = acc[nt][g * 4 + rr] + bv;
                if (PH == 1) {
                    v = fmaxf(v, 0.f);
                    p.o16[(size_t)(rb + rr) * 512 + gcol] = bf16r(v);
                } else {
                    p.of[(size_t)(rb + rr) * 128 + gcol] = v;
                }
            }
        }
    }
}

// ===========================================================================
// score_k: score = clip(tanh(aft@enc^T/sqrtE + sp*cd))*10 + cm -> out fp32.
// Tile 64x128, K=128, hi/lo both operands (3 terms). Grid 2048,
// XCD-grouped per batch (32 blocks of a bz share A/B panels in one L2).
// ===========================================================================
struct SP {
    const u16 *A0, *A1, *B0, *B1;
    float* Cf;
    const float *cd, *cm;
    const float *s1, *s2;
};

__launch_bounds__(256, 4) __global__ void score_k(SP p)
{
    const int tid = threadIdx.x;
    const int lane = tid & 63, wv = tid >> 6;
    const int wm = wv & 1, wn = wv >> 1;
    const int ln = lane & 31, hk = lane >> 5;

    const int id = blockIdx.x;
    const int xcd = id & 7, slot = id >> 3;
    const int bz = xcd * 8 + (slot >> 5);
    const int inner = slot & 31;
    const int row0 = (inner >> 2) * 64;
    const int colB0 = (inner & 3) * 128;

    __shared__ __align__(16) u16 As[2][64][40];
    __shared__ __align__(16) u16 Bs[2][128][40];

    f16v acc[2];
#pragma unroll
    for (int nt = 0; nt < 2; ++nt)
#pragma unroll
        for (int q = 0; q < 16; ++q) acc[nt][q] = 0.f;

    const int r = tid >> 2, kq = tid & 3;
    for (int k0 = 0; k0 < 128; k0 += 32) {
        size_t ga = (size_t)bz * 65536 + (size_t)(row0 + r) * 128 + k0 + kq * 8;
        *(uint4*)&As[0][r][kq * 8] = *(const uint4*)(p.A0 + ga);
        *(uint4*)&As[1][r][kq * 8] = *(const uint4*)(p.A1 + ga);
#pragma unroll
        for (int i = 0; i < 2; ++i) {
            int s = tid + i * 256;
            int rb = s >> 2, q = s & 3;
            size_t gb = (size_t)bz * 65536 + (size_t)(colB0 + rb) * 128 + k0 + q * 8;
            *(uint4*)&Bs[0][rb][q * 8] = *(const uint4*)(p.B0 + gb);
            *(uint4*)&Bs[1][rb][q * 8] = *(const uint4*)(p.B1 + gb);
        }
        __syncthreads();
#pragma unroll
        for (int s = 0; s < 2; ++s) {
            bf8 ah = *(const bf8*)&As[0][wm * 32 + ln][s * 16 + hk * 8];
            bf8 al = *(const bf8*)&As[1][wm * 32 + ln][s * 16 + hk * 8];
#pragma unroll
            for (int nt = 0; nt < 2; ++nt) {
                bf8 bh = *(const bf8*)&Bs[0][wn * 64 + nt * 32 + ln][s * 16 + hk * 8];
                bf8 bl = *(const bf8*)&Bs[1][wn * 64 + nt * 32 + ln][s * 16 + hk * 8];
                acc[nt] = MFMA(ah, bh, acc[nt]);
                acc[nt] = MFMA(ah, bl, acc[nt]);
                acc[nt] = MFMA(al, bh, acc[nt]);
            }
        }
        __syncthreads();
    }

    const float sp = p.s1[0] * p.s2[0];
#pragma unroll
    for (int nt = 0; nt < 2; ++nt) {
        int gn = colB0 + wn * 64 + nt * 32 + ln;
#pragma unroll
        for (int g = 0; g < 4; ++g) {
            int rb = row0 + wm * 32 + g * 8 + hk * 4;
#pragma unroll
            for (int rr = 0; rr < 4; ++rr) {
                float v = acc[nt][g * 4 + rr];
                size_t ix = (size_t)bz * 262144 + (size_t)(rb + rr) * 512 + gn;
                float sc = fmaf(v, SQRT_E_INV, sp * p.cd[ix]);
                float e2 = __expf(2.f * sc);
                float th = 1.f - 2.f / (e2 + 1.f);
                p.Cf[ix] = 10.f * th + p.cm[ix];
            }
        }
    }
}

// ===========================================================================
// InstanceNorm over nodes, residual fused.
// MODE1: val = (ah+al) + (g0+g1)  [two bf16 planes];  MODE2: val = (ah+al) + f1
// ===========================================================================
template <int MODE>
__launch_bounds__(256) __global__ void inorm_k(
    const u16* __restrict__ ah, const u16* __restrict__ al,
    const u16* __restrict__ g0, const u16* __restrict__ g1,
    const float* __restrict__ f1,
    const float* __restrict__ nw, const float* __restrict__ nbv,
    u16* __restrict__ oh, u16* __restrict__ ol)
{
    const int bb = blockIdx.x, e0 = blockIdx.y * 16;
    const int tid = threadIdx.x, el = tid & 3, no = tid >> 2;
    const size_t base = (size_t)bb * N_ * E_ + e0 + el * 4;

    float4 vals[8];
    float s1x = 0, s1y = 0, s1z = 0, s1w = 0;
    float s2x = 0, s2y = 0, s2z = 0, s2w = 0;
#pragma unroll
    for (int i = 0; i < 8; ++i) {
        int n = no * 8 + i;
        size_t ad = base + (size_t)n * E_;
        uint2 h2 = *(const uint2*)(ah + ad);
        uint2 l2 = *(const uint2*)(al + ad);
        float x0 = bf2f((u16)h2.x) + bf2f((u16)l2.x);
        float x1 = bf2f((u16)(h2.x >> 16)) + bf2f((u16)(l2.x >> 16));
        float x2 = bf2f((u16)h2.y) + bf2f((u16)l2.y);
        float x3 = bf2f((u16)(h2.y >> 16)) + bf2f((u16)(l2.y >> 16));
        float4 v;
        if (MODE == 1) {
            uint2 a2 = *(const uint2*)(g0 + ad);
            uint2 b2 = *(const uint2*)(g1 + ad);
            v.x = x0 + bf2f((u16)a2.x) + bf2f((u16)b2.x);
            v.y = x1 + bf2f((u16)(a2.x >> 16)) + bf2f((u16)(b2.x >> 16));
            v.z = x2 + bf2f((u16)a2.y) + bf2f((u16)b2.y);
            v.w = x3 + bf2f((u16)(a2.y >> 16)) + bf2f((u16)(b2.y >> 16));
        } else {
            float4 ff = *(const float4*)(f1 + ad);
            v.x = x0 + ff.x; v.y = x1 + ff.y; v.z = x2 + ff.z; v.w = x3 + ff.w;
        }
        vals[i] = v;
        s1x += v.x; s1y += v.y; s1z += v.z; s1w += v.w;
        s2x = fmaf(v.x, v.x, s2x); s2y = fmaf(v.y, v.y, s2y);
        s2z = fmaf(v.z, v.z, s2z); s2w = fmaf(v.w, v.w, s2w);
    }

    __shared__ float4 r1[256], r2[256];
    r1[tid] = make_float4(s1x, s1y, s1z, s1w);
    r2[tid] = make_float4(s2x, s2y, s2z, s2w);
    __syncthreads();
    for (int s = 128; s >= 4; s >>= 1) {
        if (tid < s) {
            float4 u = r1[tid], w = r1[tid + s];
            r1[tid] = make_float4(u.x + w.x, u.y + w.y, u.z + w.z, u.w + w.w);
            float4 pq = r2[tid], q = r2[tid + s];
            r2[tid] = make_float4(pq.x + q.x, pq.y + q.y, pq.z + q.z, pq.w + q.w);
        }
        __syncthreads();
    }
    __shared__ float4 mu_s[4], rs_s[4];
    if (tid < 4) {
        float4 m = r1[tid], q = r2[tid];
        m.x *= (1.f / N_); m.y *= (1.f / N_); m.z *= (1.f / N_); m.w *= (1.f / N_);
        q.x *= (1.f / N_); q.y *= (1.f / N_); q.z *= (1.f / N_); q.w *= (1.f / N_);
        float4 rs;
        rs.x = rsqrtf(q.x - m.x * m.x + 1e-5f);
        rs.y = rsqrtf(q.y - m.y * m.y + 1e-5f);
        rs.z = rsqrtf(q.z - m.z * m.z + 1e-5f);
        rs.w = rsqrtf(q.w - m.w * m.w + 1e-5f);
        mu_s[tid] = m; rs_s[tid] = rs;
    }
    __syncthreads();
    float4 mu = mu_s[el], rs = rs_s[el];
    float4 w4 = *(const float4*)(nw + e0 + el * 4);
    float4 b4 = *(const float4*)(nbv + e0 + el * 4);
#pragma unroll
    for (int i = 0; i < 8; ++i) {
        size_t ad = base + (size_t)(no * 8 + i) * E_;
        float4 v = vals[i];
        v.x = fmaf((v.x - mu.x) * rs.x, w4.x, b4.x);
        v.y = fmaf((v.y - mu.y) * rs.y, w4.y, b4.y);
        v.z = fmaf((v.z - mu.z) * rs.z, w4.z, b4.z);
        v.w = fmaf((v.w - mu.w) * rs.w, w4.w, b4.w);
        u16 h0 = bf16r(v.x), h1 = bf16r(v.y), h2v = bf16r(v.z), h3 = bf16r(v.w);
        u16 l0 = bf16r(v.x - bf2f(h0)), l1 = bf16r(v.y - bf2f(h1));
        u16 l2v = bf16r(v.z - bf2f(h2v)), l3 = bf16r(v.w - bf2f(h3));
        uint2 ph, pl;
        ph.x = h0 | ((unsigned)h1 << 16); ph.y = h2v | ((unsigned)h3 << 16);
        pl.x = l0 | ((unsigned)l1 << 16); pl.y = l2v | ((unsigned)l3 << 16);
        *(uint2*)(oh + ad) = ph;
        *(uint2*)(ol + ad) = pl;
    }
}

// ===========================================================================
__global__ void wprep_k(const float* __restrict__ W, u16* __restrict__ Th,
                        u16* __restrict__ Tl, int K, int N)
{
    const int z = blockIdx.z;
    const float* Wz = W + (size_t)z * K * N;
    u16* Hh = Th + (size_t)z * K * N;
    u16* Hl = Tl + (size_t)z * K * N;
    __shared__ float t[32][33];
    const int j = threadIdx.x & 31, i0 = threadIdx.x >> 5;
    const int k0 = blockIdx.x * 32, n0 = blockIdx.y * 32;
    for (int i = i0; i < 32; i += 8)
        t[i][j] = Wz[(size_t)(k0 + i) * N + n0 + j];
    __syncthreads();
    for (int i = i0; i < 32; i += 8) {
        float v = t[j][i];
        u16 h = bf16r(v);
        u16 l = bf16r(v - bf2f(h));
        size_t o = (size_t)(n0 + i) * K + k0 + j;
        Hh[o] = h; Hl[o] = l;
    }
}

__global__ void embed_k(const float* __restrict__ data, const float* __restrict__ W,
                        const float* __restrict__ bias,
                        u16* __restrict__ xh, u16* __restrict__ xl)
{
    size_t idx = (size_t)blockIdx.x * 256 + threadIdx.x;
    int e = idx & 127;
    size_t bn = idx >> 7;
    float v = fmaf(data[bn * 2], W[e], fmaf(data[bn * 2 + 1], W[128 + e], bias[e]));
    u16 h = bf16r(v);
    xh[idx] = h;
    xl[idx] = bf16r(v - bf2f(h));
}

__launch_bounds__(512) __global__
void gq_k(const u16* __restrict__ xh, const u16* __restrict__ xl,
          const float* __restrict__ dWq, float* __restrict__ gq)
{
    int b = blockIdx.x;
    int tid = threadIdx.x;
    int e = tid & 127, qd = tid >> 7;
    float s = 0.f;
    for (int n = qd; n < N_; n += 4) {
        size_t ix = ((size_t)b * N_ + n) * E_ + e;
        s += bf2f(xh[ix]) + bf2f(xl[ix]);
    }
    __shared__ float part[512];
    __shared__ float gm[128];
    part[tid] = s;
    __syncthreads();
    if (tid < 128)
        gm[tid] = (part[tid] + part[tid + 128] + part[tid + 256] + part[tid + 384]) *
                  (1.f / N_);
    __syncthreads();
    if (tid < 128) {
        float acc = 0.f;
        for (int kk = 0; kk < 128; ++kk) acc = fmaf(gm[kk], dWq[kk * 128 + tid], acc);
        gq[b * 128 + tid] = acc;
    }
}

__global__ void dec_aft_k(const float* __restrict__ gq, const float* __restrict__ cap,
                          const float* __restrict__ dWq,
                          const u16* __restrict__ rh, const u16* __restrict__ rl,
                          u16* __restrict__ oh, u16* __restrict__ ol)
{
    size_t idx = (size_t)blockIdx.x * 256 + threadIdx.x;
    int e = idx & 127;
    size_t bp = idx >> 7;
    int b = (int)(bp >> 9);
    float q = fmaf(cap[bp], dWq[128 * 128 + e], gq[b * 128 + e]);
    float sg = 1.f / (1.f + __expf(-q));
    float v = sg * (bf2f(rh[idx]) + bf2f(rl[idx]));
    u16 h = bf16r(v);
    oh[idx] = h;
    ol[idx] = bf16r(v - bf2f(h));
}

__launch_bounds__(256) __global__ void softmax_k(float* __restrict__ out)
{
    int row = blockIdx.x * 4 + (threadIdx.x >> 6);
    int lane = threadIdx.x & 63;
    float* p = out + (size_t)row * 512 + lane * 8;
    float4 v0 = *(float4*)p;
    float4 v1 = *(float4*)(p + 4);
    float m = fmaxf(fmaxf(fmaxf(v0.x, v0.y), fmaxf(v0.z, v0.w)),
                    fmaxf(fmaxf(v1.x, v1.y), fmaxf(v1.z, v1.w)));
#pragma unroll
    for (int o = 32; o; o >>= 1) m = fmaxf(m, __shfl_xor(m, o));
    v0.x = __expf(v0.x - m); v0.y = __expf(v0.y - m);
    v0.z = __expf(v0.z - m); v0.w = __expf(v0.w - m);
    v1.x = __expf(v1.x - m); v1.y = __expf(v1.y - m);
    v1.z = __expf(v1.z - m); v1.w = __expf(v1.w - m);
    float s = v0.x + v0.y + v0.z + v0.w + v1.x + v1.y + v1.z + v1.w;
#pragma unroll
    for (int o = 32; o; o >>= 1) s += __shfl_xor(s, o);
    float inv = 1.f / s;
    v0.x *= inv; v0.y *= inv; v0.z *= inv; v0.w *= inv;
    v1.x *= inv; v1.y *= inv; v1.z *= inv; v1.w *= inv;
    *(float4*)p = v0;
    *(float4*)(p + 4) = v1;
}

// ===========================================================================
extern "C" void kernel_launch(void* const* d_in, const int* in_sizes, int n_in,
                              void* d_out, int out_size, void* d_ws, size_t ws_size,
                              hipStream_t stream)
{
    const float* data      = (const float*)d_in[0];
    const float* dist      = (const float*)d_in[1];
    const float* cur_dist  = (const float*)d_in[2];
    const float* capacity  = (const float*)d_in[3];
    const float* ninf      = (const float*)d_in[4];
    const float* log_scale = (const float*)d_in[5];
    const float* emb_W     = (const float*)d_in[6];
    const float* emb_b     = (const float*)d_in[7];
    const float* Wq        = (const float*)d_in[8];
    const float* Wk        = (const float*)d_in[9];
    const float* Wv        = (const float*)d_in[10];
    const float* aft_alpha = (const float*)d_in[11];
    const float* n1_w      = (const float*)d_in[12];
    const float* n1_b      = (const float*)d_in[13];
    const float* ffW1      = (const float*)d_in[14];
    const float* ffb1      = (const float*)d_in[15];
    const float* ffW2      = (const float*)d_in[16];
    const float* ffb2      = (const float*)d_in[17];
    const float* n2_w      = (const float*)d_in[18];
    const float* n2_b      = (const float*)d_in[19];
    const float* dWq       = (const float*)d_in[20];
    const float* dWk       = (const float*)d_in[21];
    const float* dWv       = (const float*)d_in[22];
    const float* dec_alpha = (const float*)d_in[23];
    const float* p_alpha   = (const float*)d_in[24];
    float* out = (float*)d_out;

    char* W = (char*)d_ws;
    size_t off = 0;
    auto take = [&](size_t n) { void* pp = W + off; off += (n + 255) & ~(size_t)255; return pp; };
    const size_t SZP = (size_t)B_ * N_ * E_ * 2;   // 8 MB bf16 plane

    u16* xh   = (u16*)take(SZP);
    u16* xl   = (u16*)take(SZP);
    u16* hh   = (u16*)take(SZP);
    u16* hl   = (u16*)take(SZP);
    // contiguous region: sq16(8) + gh(8) + gl(8) + y2t(16) = 40 MB; ff1 (32MB)
    // overlays the first 32 MB (all four dead at ffn1 time).
    u16* sq16 = (u16*)take(SZP);
    u16* gh   = (u16*)take(SZP);
    u16* gl   = (u16*)take(SZP);
    u16* y2t  = (u16*)take(2 * SZP);
    float* ff2 = (float*)take((size_t)B_ * N_ * E_ * 4);   // 16 MB fp32
    u16* wqt_h = (u16*)take(196608); u16* wqt_l = (u16*)take(196608);
    u16* wkt_h = (u16*)take(196608); u16* wkt_l = (u16*)take(196608);
    u16* wvt_h = (u16*)take(196608); u16* wvt_l = (u16*)take(196608);
    u16* w1t_h = (u16*)take(786432); u16* w1t_l = (u16*)take(786432);
    u16* w2t_h = (u16*)take(786432); u16* w2t_l = (u16*)take(786432);
    u16* dkt_h = (u16*)take(32768);  u16* dkt_l = (u16*)take(32768);
    u16* dvt_h = (u16*)take(32768);  u16* dvt_l = (u16*)take(32768);
    float* gq = (float*)take(32768);
    if (ws_size < off) return;

    u16* ff1 = sq16;   // 32 MB spanning sq16+gh+gl+half of y2t

    // ---- weight prep ----
    wprep_k<<<dim3(4, 4, 6), 256, 0, stream>>>(Wq, wqt_h, wqt_l, 128, 128);
    wprep_k<<<dim3(4, 4, 6), 256, 0, stream>>>(Wk, wkt_h, wkt_l, 128, 128);
    wprep_k<<<dim3(4, 4, 6), 256, 0, stream>>>(Wv, wvt_h, wvt_l, 128, 128);
    wprep_k<<<dim3(4, 16, 6), 256, 0, stream>>>(ffW1, w1t_h, w1t_l, 128, 512);
    wprep_k<<<dim3(16, 4, 6), 256, 0, stream>>>(ffW2, w2t_h, w2t_l, 512, 128);
    wprep_k<<<dim3(4, 4, 1), 256, 0, stream>>>(dWk, dkt_h, dkt_l, 128, 128);
    wprep_k<<<dim3(4, 4, 1), 256, 0, stream>>>(dWv, dvt_h, dvt_l, 128, 128);

    embed_k<<<16384, 256, 0, stream>>>(data, emb_W, emb_b, xh, xl);

    for (int l = 0; l < L_; ++l) {
        QQ qq{};
        qq.A0 = xh; qq.A1 = xl;
        qq.B0 = wqt_h + l * 16384; qq.B1 = wqt_l + l * 16384;
        qq.sq16 = sq16;
        qvk_q_k<<<512, 256, 0, stream>>>(qq);

        QV qv{};
        qv.A0 = xh; qv.A1 = xl;
        qv.vh = wvt_h + l * 16384; qv.vl = wvt_l + l * 16384;
        qv.kh = wkt_h + l * 16384; qv.kl = wkt_l + l * 16384;
        qv.y2t = y2t;
        qvk_vk_k<<<512, 256, 0, stream>>>(qv);

        AP2 ap{};
        ap.A0 = dist; ap.B0 = y2t; ap.sq = sq16; ap.gh = gh; ap.gl = gl;
        ap.s1 = log_scale; ap.s2 = aft_alpha; ap.s2i = l;
        aft2_k<1, 1><<<512, 256, 0, stream>>>(ap);

        inorm_k<1><<<dim3(B_, 8), 256, 0, stream>>>(
            xh, xl, gh, gl, nullptr, n1_w + l * 128, n1_b + l * 128, hh, hl);

        FP fp{};
        fp.A0 = hh; fp.A1 = hl;
        fp.B0 = w1t_h + l * 65536; fp.B1 = w1t_l + l * 65536;
        fp.bias = ffb1 + l * 512; fp.o16 = ff1;
        ffn_k<1><<<2048, 256, 0, stream>>>(fp);

        fp = FP{};
        fp.A0 = ff1;
        fp.B0 = w2t_h + l * 65536; fp.B1 = w2t_l + l * 65536;
        fp.bias = ffb2 + l * 128; fp.of = ff2;
        ffn_k<2><<<dim3(512, 1), 256, 0, stream>>>(fp);

        inorm_k<2><<<dim3(B_, 8), 256, 0, stream>>>(
            hh, hl, nullptr, nullptr, ff2, n2_w + l * 128, n2_b + l * 128, xh, xl);
    }

    // ---- decoder ---- (enc = xh/xl)
    {
        QV qv{};
        qv.A0 = xh; qv.A1 = xl;
        qv.vh = dvt_h; qv.vl = dvt_l;
        qv.kh = dkt_h; qv.kl = dkt_l;
        qv.y2t = y2t;
        qvk_vk_k<<<512, 256, 0, stream>>>(qv);
        gq_k<<<B_, 512, 0, stream>>>(xh, xl, dWq, gq);

        AP2 ap{};
        ap.A0 = cur_dist; ap.A1 = ninf; ap.B0 = y2t; ap.gh = gh; ap.gl = gl;
        ap.s1 = log_scale; ap.s2 = dec_alpha; ap.s2i = 0;
        aft2_k<2, 0><<<512, 256, 0, stream>>>(ap);

        dec_aft_k<<<16384, 256, 0, stream>>>(gq, capacity, dWq, gh, gl, hh, hl);

        SP sp{};
        sp.A0 = hh; sp.A1 = hl; sp.B0 = xh; sp.B1 = xl;
        sp.Cf = out; sp.cd = cur_dist; sp.cm = ninf;
        sp.s1 = log_scale; sp.s2 = p_alpha;
        score_k<<<2048, 256, 0, stream>>>(sp);

        softmax_k<<<8192, 256, 0, stream>>>(out);
    }
}